// Round 5
// baseline (203.111 us; speedup 1.0000x reference)
//
#include <hip/hip_runtime.h>

#define NN 100000
#define NE 1600000
#define NW 25000          // NN/4 packed-byte words
#define NW4 6250          // NW/4 uint4 words
#define S  64             // edge slices
#define EPS (NE / S)      // 25000 edges per slice

typedef unsigned int uint;

// ---------------- packed-byte LDS histogram over ALL nodes (100KB LDS) ----------------
// grid (S, 2): y=0 counts dst (and records local rank), y=1 counts src
__global__ void __launch_bounds__(256)
k_hist(const int* __restrict__ src, const int* __restrict__ dst,
       uint* __restrict__ partial_in, uint* __restrict__ partial_out,
       unsigned char* __restrict__ lr) {
    __shared__ uint4 cnt4[NW4];          // 100,000 B packed byte counters
    uint* cnt = (uint*)cnt4;
    int sl = blockIdx.x;
    int y  = blockIdx.y;
    for (int w = threadIdx.x; w < NW4; w += 256) cnt4[w] = make_uint4(0, 0, 0, 0);
    __syncthreads();
    const int* key = y ? src : dst;
    int base = sl * EPS;
    for (int i4 = threadIdx.x; i4 < EPS / 4; i4 += 256) {
        int e = base + i4 * 4;
        int4 k4 = *(const int4*)&key[e];
        uint sh0 = (uint)(k4.x & 3) * 8u, sh1 = (uint)(k4.y & 3) * 8u;
        uint sh2 = (uint)(k4.z & 3) * 8u, sh3 = (uint)(k4.w & 3) * 8u;
        uint r0 = (atomicAdd(&cnt[k4.x >> 2], 1u << sh0) >> sh0) & 0xffu;
        uint r1 = (atomicAdd(&cnt[k4.y >> 2], 1u << sh1) >> sh1) & 0xffu;
        uint r2 = (atomicAdd(&cnt[k4.z >> 2], 1u << sh2) >> sh2) & 0xffu;
        uint r3 = (atomicAdd(&cnt[k4.w >> 2], 1u << sh3) >> sh3) & 0xffu;
        if (y == 0) {
            uchar4 pk = make_uchar4((unsigned char)r0, (unsigned char)r1,
                                    (unsigned char)r2, (unsigned char)r3);
            *(uchar4*)&lr[e] = pk;
        }
    }
    __syncthreads();
    uint4* dp = (uint4*)((y ? partial_out : partial_in) + (size_t)sl * NW);
    for (int w = threadIdx.x; w < NW4; w += 256) dp[w] = cnt4[w];
}

// ---------------- byte-SIMD prefix over slices + degrees + norms ----------------
__global__ void k_degnorm(uint* __restrict__ partial_in, const uint* __restrict__ partial_out,
                          int* __restrict__ deg_in, float* __restrict__ norm_in,
                          float* __restrict__ norm_out) {
    int w = blockIdx.x * blockDim.x + threadIdx.x;
    if (w >= NW) return;
    uint run = 0;
#pragma unroll 8
    for (int s = 0; s < S; ++s) {
        uint u = partial_in[(size_t)s * NW + w];
        partial_in[(size_t)s * NW + w] = run;
        run += u;
    }
    uint ro = 0;
#pragma unroll 8
    for (int s = 0; s < S; ++s) ro += partial_out[(size_t)s * NW + w];
    int4 dg;
    float4 fi, fo;
    {
        int d0 = run & 0xff, d1 = (run >> 8) & 0xff, d2 = (run >> 16) & 0xff, d3 = (run >> 24) & 0xff;
        dg = make_int4(d0, d1, d2, d3);
        fi.x = d0 > 0 ? rsqrtf((float)d0) : 1.0f;
        fi.y = d1 > 0 ? rsqrtf((float)d1) : 1.0f;
        fi.z = d2 > 0 ? rsqrtf((float)d2) : 1.0f;
        fi.w = d3 > 0 ? rsqrtf((float)d3) : 1.0f;
        int o0 = ro & 0xff, o1 = (ro >> 8) & 0xff, o2 = (ro >> 16) & 0xff, o3 = (ro >> 24) & 0xff;
        fo.x = o0 > 0 ? rsqrtf((float)o0) : 1.0f;
        fo.y = o1 > 0 ? rsqrtf((float)o1) : 1.0f;
        fo.z = o2 > 0 ? rsqrtf((float)o2) : 1.0f;
        fo.w = o3 > 0 ? rsqrtf((float)o3) : 1.0f;
    }
    *(int4*)&deg_in[w * 4]     = dg;
    *(float4*)&norm_in[w * 4]  = fi;
    *(float4*)&norm_out[w * 4] = fo;
}

// ---------------- row_ofs: exclusive scan of deg_in ----------------

__global__ void k_bsum(const int* __restrict__ deg_in, int* __restrict__ bsum) {
    __shared__ int red[4];
    int base = blockIdx.x * 1024;
    int s = 0;
    for (int i = threadIdx.x; i < 1024; i += 256) {
        int n = base + i;
        s += (n < NN) ? deg_in[n] : 0;
    }
#pragma unroll
    for (int off = 32; off; off >>= 1) s += __shfl_xor(s, off, 64);
    if ((threadIdx.x & 63) == 0) red[threadIdx.x >> 6] = s;
    __syncthreads();
    if (threadIdx.x == 0) bsum[blockIdx.x] = red[0] + red[1] + red[2] + red[3];
}

__global__ void k_bscan(const int* __restrict__ bsum, int* __restrict__ bofs,
                        int* __restrict__ row_ofs, int nb) {
    if (blockIdx.x == 0 && threadIdx.x == 0) {
        int run = 0;
        for (int i = 0; i < nb; ++i) { bofs[i] = run; run += bsum[i]; }
        bofs[nb] = run;
        row_ofs[NN] = run;   // == NE
    }
}

__global__ void k_scan(const int* __restrict__ deg_in, const int* __restrict__ bofs,
                       int* __restrict__ row_ofs) {
    __shared__ int wofs[4];
    int t = threadIdx.x;
    int base = blockIdx.x * 1024 + t * 4;
    int d[4];
#pragma unroll
    for (int k = 0; k < 4; ++k) {
        int n = base + k;
        d[k] = (n < NN) ? deg_in[n] : 0;
    }
    int loc = d[0] + d[1] + d[2] + d[3];
    int v = loc;
    int lane = t & 63;
#pragma unroll
    for (int off = 1; off < 64; off <<= 1) {
        int u = __shfl_up(v, off, 64);
        if (lane >= off) v += u;
    }
    if (lane == 63) wofs[t >> 6] = v;
    __syncthreads();
    int w = t >> 6;
    int wbase = 0;
    if (w > 0) wbase += wofs[0];
    if (w > 1) wbase += wofs[1];
    if (w > 2) wbase += wofs[2];
    int excl = bofs[blockIdx.x] + wbase + (v - loc);
#pragma unroll
    for (int k = 0; k < 4; ++k) {
        int n = base + k;
        if (n < NN) { row_ofs[n] = excl; excl += d[k]; }
    }
}

// ---------------- atomic-free CSR fill ----------------
__global__ void k_replay(const int* __restrict__ src, const int* __restrict__ dst,
                         const uint* __restrict__ base_bytes, const unsigned char* __restrict__ lr,
                         const int* __restrict__ row_ofs, int* __restrict__ csr_src) {
    int e = blockIdx.x * blockDim.x + threadIdx.x;
    if (e < NE) {
        int d  = dst[e];
        int sl = e / EPS;
        uint pw = base_bytes[(size_t)sl * NW + (d >> 2)];
        int b = (int)((pw >> ((d & 3) * 8)) & 0xffu);
        csr_src[row_ofs[d] + b + (int)lr[e]] = src[e];
    }
}

// ---------------- pre-projected bf16 features: y = bf16((x .* norm_out) @ W1) ----------------
__device__ inline uint bfpair(float a, float b) {   // two RNE bf16 packed in a uint
    uint ua = __float_as_uint(a); ua += 0x7fffu + ((ua >> 16) & 1u);
    uint ub = __float_as_uint(b); ub += 0x7fffu + ((ub >> 16) & 1u);
    return (ua >> 16) | (ub & 0xffff0000u);
}

#define PROJ_WAVES 4096
__global__ void __launch_bounds__(256)
k_proj(const float* __restrict__ x, const float* __restrict__ norm_out,
       const float* __restrict__ W1, uint* __restrict__ xb) {
    int lane = threadIdx.x & 63;
    int wid = blockIdx.x * 4 + (threadIdx.x >> 6);   // global wave id
    float w1c[64];                                   // W1 column `lane` in regs
#pragma unroll
    for (int k = 0; k < 64; ++k) w1c[k] = W1[k * 64 + lane];
    for (int n = wid; n < NN; n += PROJ_WAVES) {
        float v = x[(size_t)n * 64 + lane] * norm_out[n];
        float s0 = 0, s1 = 0, s2 = 0, s3 = 0;
#pragma unroll
        for (int k = 0; k < 64; k += 4) {
            s0 += __shfl(v, k, 64)     * w1c[k];
            s1 += __shfl(v, k + 1, 64) * w1c[k + 1];
            s2 += __shfl(v, k + 2, 64) * w1c[k + 2];
            s3 += __shfl(v, k + 3, 64) * w1c[k + 3];
        }
        float y = (s0 + s1) + (s2 + s3);
        float yo = __shfl_xor(y, 1, 64);
        if (!(lane & 1)) xb[(size_t)n * 32 + (lane >> 1)] = bfpair(y, yo);
    }
}

// ---------------- aggregate y (bf16 gather) + relu/W2 epilogue; no LDS, no barriers ----------------
// 256 thr = 4 waves = 4 nodes/block; wave = 4 quarters of 16 lanes, each quarter
// gathers a different edge's 128B row (uint2 = 4 bf16 per lane).
__global__ void __launch_bounds__(256)
k_agg1(const int* __restrict__ csr_src, const int* __restrict__ row_ofs,
       const uint* __restrict__ xb, const float* __restrict__ norm_in,
       const float* __restrict__ norm_out,
       const float* __restrict__ b1, const float* __restrict__ W2,
       float* __restrict__ z) {
    int tid = threadIdx.x;
    int lane = tid & 63, q = lane >> 4, lq = lane & 15;
    int n = blockIdx.x * 4 + (tid >> 6);
    if (n >= NN) return;
    int beg = row_ofs[n], end = row_ofs[n + 1];
    float a0 = 0, a1 = 0, a2 = 0, a3 = 0;
    int ei = beg + q;
    for (; ei + 4 < end; ei += 8) {          // 8 edges in flight per wave
        int sA = csr_src[ei], sB = csr_src[ei + 4];
        uint2 uA = *(const uint2*)((const char*)xb + ((size_t)sA << 7) + (lq << 3));
        uint2 uB = *(const uint2*)((const char*)xb + ((size_t)sB << 7) + (lq << 3));
        a0 += __uint_as_float(uA.x << 16) + __uint_as_float(uB.x << 16);
        a1 += __uint_as_float(uA.x & 0xffff0000u) + __uint_as_float(uB.x & 0xffff0000u);
        a2 += __uint_as_float(uA.y << 16) + __uint_as_float(uB.y << 16);
        a3 += __uint_as_float(uA.y & 0xffff0000u) + __uint_as_float(uB.y & 0xffff0000u);
    }
    if (ei < end) {
        int sA = csr_src[ei];
        uint2 uA = *(const uint2*)((const char*)xb + ((size_t)sA << 7) + (lq << 3));
        a0 += __uint_as_float(uA.x << 16);
        a1 += __uint_as_float(uA.x & 0xffff0000u);
        a2 += __uint_as_float(uA.y << 16);
        a3 += __uint_as_float(uA.y & 0xffff0000u);
    }
    // combine the 4 quarters (all lanes end with full sums for feats lq*4..lq*4+3)
    a0 += __shfl_xor(a0, 16, 64); a0 += __shfl_xor(a0, 32, 64);
    a1 += __shfl_xor(a1, 16, 64); a1 += __shfl_xor(a1, 32, 64);
    a2 += __shfl_xor(a2, 16, 64); a2 += __shfl_xor(a2, 32, 64);
    a3 += __shfl_xor(a3, 16, 64); a3 += __shfl_xor(a3, 32, 64);
    // epilogue: h = relu(a*norm_in + b1); z = (h . W2) * norm_out
    float4 bb = *(const float4*)&b1[lq * 4];
    float4 ww = *(const float4*)&W2[lq * 4];
    float nin = norm_in[n];
    float h0 = fmaxf(a0 * nin + bb.x, 0.0f);
    float h1 = fmaxf(a1 * nin + bb.y, 0.0f);
    float h2 = fmaxf(a2 * nin + bb.z, 0.0f);
    float h3 = fmaxf(a3 * nin + bb.w, 0.0f);
    float zv = h0 * ww.x + h1 * ww.y + h2 * ww.z + h3 * ww.w;
#pragma unroll
    for (int off = 8; off; off >>= 1) zv += __shfl_xor(zv, off, 64);
    if (lane == 0) z[n] = zv * norm_out[n];
}

// ---------------- layer 2 gather + sigmoid ----------------
__global__ void k_out2(const int* __restrict__ csr_src, const int* __restrict__ row_ofs,
                       const float* __restrict__ z, const float* __restrict__ norm_in,
                       const float* __restrict__ b2, float* __restrict__ out) {
    int n = blockIdx.x * blockDim.x + threadIdx.x;
    if (n < NN) {
        int beg = row_ofs[n], end = row_ofs[n + 1];
        float a = 0.0f;
        int i = beg;
        for (; i + 3 < end; i += 4) {
            float z0 = z[csr_src[i]], z1 = z[csr_src[i + 1]];
            float z2 = z[csr_src[i + 2]], z3 = z[csr_src[i + 3]];
            a += (z0 + z1) + (z2 + z3);
        }
        for (; i < end; ++i) a += z[csr_src[i]];
        float v = a * norm_in[n] + b2[0];
        out[n] = 1.0f / (1.0f + expf(-v));
    }
}

// ---------------- launch ----------------

extern "C" void kernel_launch(void* const* d_in, const int* in_sizes, int n_in,
                              void* d_out, int out_size, void* d_ws, size_t ws_size,
                              hipStream_t stream) {
    const float* x   = (const float*)d_in[0];
    const int*   src = (const int*)d_in[1];
    const int*   dst = (const int*)d_in[2];
    const float* W1  = (const float*)d_in[3];
    const float* b1  = (const float*)d_in[4];
    const float* W2  = (const float*)d_in[5];
    const float* b2  = (const float*)d_in[6];
    float* out = (float*)d_out;

    // ws layout (4B words). xb (3.2M words) aliases partial_in+lr+partial_out,
    // all dead after k_replay; k_proj runs after k_replay.
    uint* W0 = (uint*)d_ws;
    uint*          partial_in  = W0;                                  // 1.6M words
    unsigned char* lr          = (unsigned char*)(W0 + 1600000);      // 400K words
    uint*          partial_out = W0 + 2000000;                        // 1.6M words
    uint*          xb          = W0;                                  // 3.2M words (phase B)
    int*           csr_src     = (int*)(W0 + 3600000);                // 1.6M words
    int*           row_ofs     = (int*)(W0 + 5200000);                // NN+1
    int*           deg_in      = row_ofs + NN + 32;                   // NN
    float*         norm_in     = (float*)(deg_in + NN);               // NN
    float*         norm_out    = norm_in + NN;                        // NN
    float*         z           = norm_out + NN;                       // NN
    int*           bsum        = (int*)(z + NN);                      // 98
    int*           bofs        = bsum + 128;                          // 99

    int nb = (NN + 1023) / 1024;   // 98

    k_hist   <<<dim3(S, 2), 256, 0, stream>>>(src, dst, partial_in, partial_out, lr);
    k_degnorm<<<(NW + 255) / 256, 256, 0, stream>>>(partial_in, partial_out,
                                                    deg_in, norm_in, norm_out);
    k_bsum   <<<nb, 256, 0, stream>>>(deg_in, bsum);
    k_bscan  <<<1, 64, 0, stream>>>(bsum, bofs, row_ofs, nb);
    k_scan   <<<nb, 256, 0, stream>>>(deg_in, bofs, row_ofs);
    k_replay <<<(NE + 255) / 256, 256, 0, stream>>>(src, dst, partial_in, lr, row_ofs, csr_src);

    k_proj   <<<PROJ_WAVES / 4, 256, 0, stream>>>(x, norm_out, W1, xb);
    k_agg1   <<<(NN + 3) / 4, 256, 0, stream>>>(csr_src, row_ofs, xb, norm_in, norm_out,
                                                b1, W2, z);
    k_out2   <<<(NN + 255) / 256, 256, 0, stream>>>(csr_src, row_ofs, z, norm_in, b2, out);
}

// Round 6
// 142.220 us; speedup vs baseline: 1.4282x; 1.4282x over previous
//
#include <hip/hip_runtime.h>

#define NN 100000
#define NE 1600000
#define NW 25000          // NN/4 packed-byte words
#define NW4 6250          // NW/4 uint4 words
#define S  64             // edge slices
#define EPS (NE / S)      // 25000 edges per slice

typedef unsigned int uint;
typedef _Float16 f16x8 __attribute__((ext_vector_type(8)));
typedef _Float16 f16x2 __attribute__((ext_vector_type(2)));
typedef float f32x4 __attribute__((ext_vector_type(4)));

// ---------------- packed-byte LDS histogram over ALL nodes (100KB LDS) ----------------
// grid (S, 2): y=0 counts dst (and records local rank), y=1 counts src
__global__ void __launch_bounds__(256)
k_hist(const int* __restrict__ src, const int* __restrict__ dst,
       uint* __restrict__ partial_in, uint* __restrict__ partial_out,
       unsigned char* __restrict__ lr) {
    __shared__ uint4 cnt4[NW4];          // 100,000 B packed byte counters
    uint* cnt = (uint*)cnt4;
    int sl = blockIdx.x;
    int y  = blockIdx.y;
    for (int w = threadIdx.x; w < NW4; w += 256) cnt4[w] = make_uint4(0, 0, 0, 0);
    __syncthreads();
    const int* key = y ? src : dst;
    int base = sl * EPS;
    for (int i4 = threadIdx.x; i4 < EPS / 4; i4 += 256) {
        int e = base + i4 * 4;
        int4 k4 = *(const int4*)&key[e];
        uint sh0 = (uint)(k4.x & 3) * 8u, sh1 = (uint)(k4.y & 3) * 8u;
        uint sh2 = (uint)(k4.z & 3) * 8u, sh3 = (uint)(k4.w & 3) * 8u;
        uint r0 = (atomicAdd(&cnt[k4.x >> 2], 1u << sh0) >> sh0) & 0xffu;
        uint r1 = (atomicAdd(&cnt[k4.y >> 2], 1u << sh1) >> sh1) & 0xffu;
        uint r2 = (atomicAdd(&cnt[k4.z >> 2], 1u << sh2) >> sh2) & 0xffu;
        uint r3 = (atomicAdd(&cnt[k4.w >> 2], 1u << sh3) >> sh3) & 0xffu;
        if (y == 0) {
            uchar4 pk = make_uchar4((unsigned char)r0, (unsigned char)r1,
                                    (unsigned char)r2, (unsigned char)r3);
            *(uchar4*)&lr[e] = pk;
        }
    }
    __syncthreads();
    uint4* dp = (uint4*)((y ? partial_out : partial_in) + (size_t)sl * NW);
    for (int w = threadIdx.x; w < NW4; w += 256) dp[w] = cnt4[w];
}

// ---------------- byte-SIMD prefix over slices + degrees + norms ----------------
__global__ void k_degnorm(uint* __restrict__ partial_in, const uint* __restrict__ partial_out,
                          int* __restrict__ deg_in, float* __restrict__ norm_in,
                          float* __restrict__ norm_out) {
    int w = blockIdx.x * blockDim.x + threadIdx.x;
    if (w >= NW) return;
    uint run = 0;
#pragma unroll 8
    for (int s = 0; s < S; ++s) {
        uint u = partial_in[(size_t)s * NW + w];
        partial_in[(size_t)s * NW + w] = run;
        run += u;
    }
    uint ro = 0;
#pragma unroll 8
    for (int s = 0; s < S; ++s) ro += partial_out[(size_t)s * NW + w];
    int4 dg;
    float4 fi, fo;
    {
        int d0 = run & 0xff, d1 = (run >> 8) & 0xff, d2 = (run >> 16) & 0xff, d3 = (run >> 24) & 0xff;
        dg = make_int4(d0, d1, d2, d3);
        fi.x = d0 > 0 ? rsqrtf((float)d0) : 1.0f;
        fi.y = d1 > 0 ? rsqrtf((float)d1) : 1.0f;
        fi.z = d2 > 0 ? rsqrtf((float)d2) : 1.0f;
        fi.w = d3 > 0 ? rsqrtf((float)d3) : 1.0f;
        int o0 = ro & 0xff, o1 = (ro >> 8) & 0xff, o2 = (ro >> 16) & 0xff, o3 = (ro >> 24) & 0xff;
        fo.x = o0 > 0 ? rsqrtf((float)o0) : 1.0f;
        fo.y = o1 > 0 ? rsqrtf((float)o1) : 1.0f;
        fo.z = o2 > 0 ? rsqrtf((float)o2) : 1.0f;
        fo.w = o3 > 0 ? rsqrtf((float)o3) : 1.0f;
    }
    *(int4*)&deg_in[w * 4]     = dg;
    *(float4*)&norm_in[w * 4]  = fi;
    *(float4*)&norm_out[w * 4] = fo;
}

// ---------------- row_ofs: exclusive scan of deg_in ----------------

__global__ void k_bsum(const int* __restrict__ deg_in, int* __restrict__ bsum) {
    __shared__ int red[4];
    int base = blockIdx.x * 1024;
    int s = 0;
    for (int i = threadIdx.x; i < 1024; i += 256) {
        int n = base + i;
        s += (n < NN) ? deg_in[n] : 0;
    }
#pragma unroll
    for (int off = 32; off; off >>= 1) s += __shfl_xor(s, off, 64);
    if ((threadIdx.x & 63) == 0) red[threadIdx.x >> 6] = s;
    __syncthreads();
    if (threadIdx.x == 0) bsum[blockIdx.x] = red[0] + red[1] + red[2] + red[3];
}

__global__ void k_bscan(const int* __restrict__ bsum, int* __restrict__ bofs,
                        int* __restrict__ row_ofs, int nb) {
    if (blockIdx.x == 0 && threadIdx.x == 0) {
        int run = 0;
        for (int i = 0; i < nb; ++i) { bofs[i] = run; run += bsum[i]; }
        bofs[nb] = run;
        row_ofs[NN] = run;   // == NE
    }
}

__global__ void k_scan(const int* __restrict__ deg_in, const int* __restrict__ bofs,
                       int* __restrict__ row_ofs) {
    __shared__ int wofs[4];
    int t = threadIdx.x;
    int base = blockIdx.x * 1024 + t * 4;
    int d[4];
#pragma unroll
    for (int k = 0; k < 4; ++k) {
        int n = base + k;
        d[k] = (n < NN) ? deg_in[n] : 0;
    }
    int loc = d[0] + d[1] + d[2] + d[3];
    int v = loc;
    int lane = t & 63;
#pragma unroll
    for (int off = 1; off < 64; off <<= 1) {
        int u = __shfl_up(v, off, 64);
        if (lane >= off) v += u;
    }
    if (lane == 63) wofs[t >> 6] = v;
    __syncthreads();
    int w = t >> 6;
    int wbase = 0;
    if (w > 0) wbase += wofs[0];
    if (w > 1) wbase += wofs[1];
    if (w > 2) wbase += wofs[2];
    int excl = bofs[blockIdx.x] + wbase + (v - loc);
#pragma unroll
    for (int k = 0; k < 4; ++k) {
        int n = base + k;
        if (n < NN) { row_ofs[n] = excl; excl += d[k]; }
    }
}

// ---------------- atomic-free CSR fill ----------------
__global__ void k_replay(const int* __restrict__ src, const int* __restrict__ dst,
                         const uint* __restrict__ base_bytes, const unsigned char* __restrict__ lr,
                         const int* __restrict__ row_ofs, int* __restrict__ csr_src) {
    int e = blockIdx.x * blockDim.x + threadIdx.x;
    if (e < NE) {
        int d  = dst[e];
        int sl = e / EPS;
        uint pw = base_bytes[(size_t)sl * NW + (d >> 2)];
        int b = (int)((pw >> ((d & 3) * 8)) & 0xffu);
        csr_src[row_ofs[d] + b + (int)lr[e]] = src[e];
    }
}

// ---------------- MFMA projection: y = f16((x .* norm_out) @ W1) ----------------
// one wave per 16-node tile; A-frag: row = lane&15, k = (lane>>4)*8+j (fused
// norm_out scale + f16 cvt); B-frags (W1) hoisted into 32 VGPRs; 8 MFMAs/tile.
__global__ void __launch_bounds__(256)
k_proj(const float* __restrict__ x, const float* __restrict__ norm_out,
       const float* __restrict__ W1, _Float16* __restrict__ y) {
    int lane = threadIdx.x & 63;
    int col  = lane & 15;
    int kh   = lane >> 4;
    // B fragments: wf[t][s][j] = W1[s*32 + kh*8 + j][t*16 + col]
    f16x8 wf[4][2];
#pragma unroll
    for (int t = 0; t < 4; ++t)
#pragma unroll
        for (int s = 0; s < 2; ++s)
#pragma unroll
            for (int j = 0; j < 8; ++j)
                wf[t][s][j] = (_Float16)W1[(s * 32 + kh * 8 + j) * 64 + t * 16 + col];
    int tile = blockIdx.x * 4 + (threadIdx.x >> 6);
    if (tile >= NN / 16) return;
    int base = tile * 16;
    int row  = base + col;
    float no = norm_out[row];
    const float* xr = &x[(size_t)row * 64 + kh * 8];
    f16x8 af[2];
#pragma unroll
    for (int s = 0; s < 2; ++s) {
        float4 v0 = *(const float4*)&xr[s * 32];
        float4 v1 = *(const float4*)&xr[s * 32 + 4];
        af[s][0] = (_Float16)(v0.x * no); af[s][1] = (_Float16)(v0.y * no);
        af[s][2] = (_Float16)(v0.z * no); af[s][3] = (_Float16)(v0.w * no);
        af[s][4] = (_Float16)(v1.x * no); af[s][5] = (_Float16)(v1.y * no);
        af[s][6] = (_Float16)(v1.z * no); af[s][7] = (_Float16)(v1.w * no);
    }
    f32x4 acc[4];
#pragma unroll
    for (int t = 0; t < 4; ++t) acc[t] = (f32x4){0.f, 0.f, 0.f, 0.f};
#pragma unroll
    for (int t = 0; t < 4; ++t) {
        acc[t] = __builtin_amdgcn_mfma_f32_16x16x32_f16(af[0], wf[t][0], acc[t], 0, 0, 0);
        acc[t] = __builtin_amdgcn_mfma_f32_16x16x32_f16(af[1], wf[t][1], acc[t], 0, 0, 0);
    }
    // C/D layout: col = lane&15, row = (lane>>4)*4 + reg
#pragma unroll
    for (int t = 0; t < 4; ++t)
#pragma unroll
        for (int r = 0; r < 4; ++r)
            y[(size_t)(base + kh * 4 + r) * 64 + t * 16 + col] = (_Float16)acc[t][r];
}

// ---------------- aggregate y (f16 gather) + relu/W2 epilogue; no LDS, no barriers ----------------
// 256 thr = 4 waves = 4 nodes/block; wave = 4 quarters of 16 lanes, each quarter
// gathers a different edge's 128B row (uint2 = 4 f16 per lane).
__device__ inline float2 up2(uint u) {
    f16x2 p = __builtin_bit_cast(f16x2, u);
    return make_float2((float)p.x, (float)p.y);
}

__global__ void __launch_bounds__(256)
k_agg1(const int* __restrict__ csr_src, const int* __restrict__ row_ofs,
       const uint* __restrict__ xb, const float* __restrict__ norm_in,
       const float* __restrict__ norm_out,
       const float* __restrict__ b1, const float* __restrict__ W2,
       float* __restrict__ z) {
    int tid = threadIdx.x;
    int lane = tid & 63, q = lane >> 4, lq = lane & 15;
    int n = blockIdx.x * 4 + (tid >> 6);
    if (n >= NN) return;
    int beg = row_ofs[n], end = row_ofs[n + 1];
    float a0 = 0, a1 = 0, a2 = 0, a3 = 0;
    int ei = beg + q;
    for (; ei + 4 < end; ei += 8) {          // 8 edges in flight per wave
        int sA = csr_src[ei], sB = csr_src[ei + 4];
        uint2 uA = *(const uint2*)((const char*)xb + ((size_t)sA << 7) + (lq << 3));
        uint2 uB = *(const uint2*)((const char*)xb + ((size_t)sB << 7) + (lq << 3));
        float2 pA0 = up2(uA.x), pA1 = up2(uA.y), pB0 = up2(uB.x), pB1 = up2(uB.y);
        a0 += pA0.x + pB0.x;
        a1 += pA0.y + pB0.y;
        a2 += pA1.x + pB1.x;
        a3 += pA1.y + pB1.y;
    }
    if (ei < end) {
        int sA = csr_src[ei];
        uint2 uA = *(const uint2*)((const char*)xb + ((size_t)sA << 7) + (lq << 3));
        float2 pA0 = up2(uA.x), pA1 = up2(uA.y);
        a0 += pA0.x; a1 += pA0.y; a2 += pA1.x; a3 += pA1.y;
    }
    // combine the 4 quarters
    a0 += __shfl_xor(a0, 16, 64); a0 += __shfl_xor(a0, 32, 64);
    a1 += __shfl_xor(a1, 16, 64); a1 += __shfl_xor(a1, 32, 64);
    a2 += __shfl_xor(a2, 16, 64); a2 += __shfl_xor(a2, 32, 64);
    a3 += __shfl_xor(a3, 16, 64); a3 += __shfl_xor(a3, 32, 64);
    // epilogue: h = relu(a*norm_in + b1); z = (h . W2) * norm_out
    float4 bb = *(const float4*)&b1[lq * 4];
    float4 ww = *(const float4*)&W2[lq * 4];
    float nin = norm_in[n];
    float h0 = fmaxf(a0 * nin + bb.x, 0.0f);
    float h1 = fmaxf(a1 * nin + bb.y, 0.0f);
    float h2 = fmaxf(a2 * nin + bb.z, 0.0f);
    float h3 = fmaxf(a3 * nin + bb.w, 0.0f);
    float zv = h0 * ww.x + h1 * ww.y + h2 * ww.z + h3 * ww.w;
#pragma unroll
    for (int off = 8; off; off >>= 1) zv += __shfl_xor(zv, off, 64);
    if (lane == 0) z[n] = zv * norm_out[n];
}

// ---------------- layer 2 gather + sigmoid ----------------
__global__ void k_out2(const int* __restrict__ csr_src, const int* __restrict__ row_ofs,
                       const float* __restrict__ z, const float* __restrict__ norm_in,
                       const float* __restrict__ b2, float* __restrict__ out) {
    int n = blockIdx.x * blockDim.x + threadIdx.x;
    if (n < NN) {
        int beg = row_ofs[n], end = row_ofs[n + 1];
        float a = 0.0f;
        int i = beg;
        for (; i + 3 < end; i += 4) {
            float z0 = z[csr_src[i]], z1 = z[csr_src[i + 1]];
            float z2 = z[csr_src[i + 2]], z3 = z[csr_src[i + 3]];
            a += (z0 + z1) + (z2 + z3);
        }
        for (; i < end; ++i) a += z[csr_src[i]];
        float v = a * norm_in[n] + b2[0];
        out[n] = 1.0f / (1.0f + expf(-v));
    }
}

// ---------------- launch ----------------

extern "C" void kernel_launch(void* const* d_in, const int* in_sizes, int n_in,
                              void* d_out, int out_size, void* d_ws, size_t ws_size,
                              hipStream_t stream) {
    const float* x   = (const float*)d_in[0];
    const int*   src = (const int*)d_in[1];
    const int*   dst = (const int*)d_in[2];
    const float* W1  = (const float*)d_in[3];
    const float* b1  = (const float*)d_in[4];
    const float* W2  = (const float*)d_in[5];
    const float* b2  = (const float*)d_in[6];
    float* out = (float*)d_out;

    // ws layout (4B words). xb (3.2M words) aliases partial_in+lr+partial_out,
    // all dead after k_replay; k_proj runs after k_replay.
    uint* W0 = (uint*)d_ws;
    uint*          partial_in  = W0;                                  // 1.6M words
    unsigned char* lr          = (unsigned char*)(W0 + 1600000);      // 400K words
    uint*          partial_out = W0 + 2000000;                        // 1.6M words
    uint*          xb          = W0;                                  // 3.2M words (phase B)
    int*           csr_src     = (int*)(W0 + 3600000);                // 1.6M words
    int*           row_ofs     = (int*)(W0 + 5200000);                // NN+1
    int*           deg_in      = row_ofs + NN + 32;                   // NN
    float*         norm_in     = (float*)(deg_in + NN);               // NN
    float*         norm_out    = norm_in + NN;                        // NN
    float*         z           = norm_out + NN;                       // NN
    int*           bsum        = (int*)(z + NN);                      // 98
    int*           bofs        = bsum + 128;                          // 99

    int nb = (NN + 1023) / 1024;   // 98

    k_hist   <<<dim3(S, 2), 256, 0, stream>>>(src, dst, partial_in, partial_out, lr);
    k_degnorm<<<(NW + 255) / 256, 256, 0, stream>>>(partial_in, partial_out,
                                                    deg_in, norm_in, norm_out);
    k_bsum   <<<nb, 256, 0, stream>>>(deg_in, bsum);
    k_bscan  <<<1, 64, 0, stream>>>(bsum, bofs, row_ofs, nb);
    k_scan   <<<nb, 256, 0, stream>>>(deg_in, bofs, row_ofs);
    k_replay <<<(NE + 255) / 256, 256, 0, stream>>>(src, dst, partial_in, lr, row_ofs, csr_src);

    k_proj   <<<(NN / 16 + 3) / 4, 256, 0, stream>>>(x, norm_out, W1, (_Float16*)xb);
    k_agg1   <<<(NN + 3) / 4, 256, 0, stream>>>(csr_src, row_ofs, xb, norm_in, norm_out,
                                                b1, W2, z);
    k_out2   <<<(NN + 255) / 256, 256, 0, stream>>>(csr_src, row_ofs, z, norm_in, b2, out);
}

// Round 7
// 133.235 us; speedup vs baseline: 1.5245x; 1.0674x over previous
//
#include <hip/hip_runtime.h>

#define NN 100000
#define NE 1600000
#define NW 25000          // NN/4 packed-byte words
#define NW4 6250          // NW/4 uint4 words
#define S  64             // edge slices
#define EPS (NE / S)      // 25000 edges per slice
#define AGG_GRID 2048     // persistent blocks for k_agg1 (8 per CU)

typedef unsigned int uint;
typedef _Float16 f16x8 __attribute__((ext_vector_type(8)));
typedef _Float16 f16x2 __attribute__((ext_vector_type(2)));
typedef float f32x4 __attribute__((ext_vector_type(4)));

// ---------------- packed-byte LDS histogram over ALL nodes (100KB LDS) ----------------
// grid (S, 2): y=0 counts dst (and records local rank), y=1 counts src
__global__ void __launch_bounds__(256)
k_hist(const int* __restrict__ src, const int* __restrict__ dst,
       uint* __restrict__ partial_in, uint* __restrict__ partial_out,
       unsigned char* __restrict__ lr) {
    __shared__ uint4 cnt4[NW4];          // 100,000 B packed byte counters
    uint* cnt = (uint*)cnt4;
    int sl = blockIdx.x;
    int y  = blockIdx.y;
    for (int w = threadIdx.x; w < NW4; w += 256) cnt4[w] = make_uint4(0, 0, 0, 0);
    __syncthreads();
    const int* key = y ? src : dst;
    int base = sl * EPS;
    for (int i4 = threadIdx.x; i4 < EPS / 4; i4 += 256) {
        int e = base + i4 * 4;
        int4 k4 = *(const int4*)&key[e];
        uint sh0 = (uint)(k4.x & 3) * 8u, sh1 = (uint)(k4.y & 3) * 8u;
        uint sh2 = (uint)(k4.z & 3) * 8u, sh3 = (uint)(k4.w & 3) * 8u;
        uint r0 = (atomicAdd(&cnt[k4.x >> 2], 1u << sh0) >> sh0) & 0xffu;
        uint r1 = (atomicAdd(&cnt[k4.y >> 2], 1u << sh1) >> sh1) & 0xffu;
        uint r2 = (atomicAdd(&cnt[k4.z >> 2], 1u << sh2) >> sh2) & 0xffu;
        uint r3 = (atomicAdd(&cnt[k4.w >> 2], 1u << sh3) >> sh3) & 0xffu;
        if (y == 0) {
            uchar4 pk = make_uchar4((unsigned char)r0, (unsigned char)r1,
                                    (unsigned char)r2, (unsigned char)r3);
            *(uchar4*)&lr[e] = pk;
        }
    }
    __syncthreads();
    uint4* dp = (uint4*)((y ? partial_out : partial_in) + (size_t)sl * NW);
    for (int w = threadIdx.x; w < NW4; w += 256) dp[w] = cnt4[w];
}

// ---------------- byte-SIMD prefix over slices + degrees + norms + block sums ----------------
// block covers 256 words = 1024 nodes (matches k_scan blocking); also emits bsum.
__global__ void k_degnorm(uint* __restrict__ partial_in, const uint* __restrict__ partial_out,
                          int* __restrict__ deg_in, float* __restrict__ norm_in,
                          float* __restrict__ norm_out, int* __restrict__ bsum) {
    __shared__ int red[4];
    int w = blockIdx.x * 256 + threadIdx.x;
    int mysum = 0;
    if (w < NW) {
        uint run = 0;
#pragma unroll 8
        for (int s = 0; s < S; ++s) {
            uint u = partial_in[(size_t)s * NW + w];
            partial_in[(size_t)s * NW + w] = run;
            run += u;
        }
        uint ro = 0;
#pragma unroll 8
        for (int s = 0; s < S; ++s) ro += partial_out[(size_t)s * NW + w];
        int4 dg;
        float4 fi, fo;
        int d0 = run & 0xff, d1 = (run >> 8) & 0xff, d2 = (run >> 16) & 0xff, d3 = (run >> 24) & 0xff;
        dg = make_int4(d0, d1, d2, d3);
        fi.x = d0 > 0 ? rsqrtf((float)d0) : 1.0f;
        fi.y = d1 > 0 ? rsqrtf((float)d1) : 1.0f;
        fi.z = d2 > 0 ? rsqrtf((float)d2) : 1.0f;
        fi.w = d3 > 0 ? rsqrtf((float)d3) : 1.0f;
        int o0 = ro & 0xff, o1 = (ro >> 8) & 0xff, o2 = (ro >> 16) & 0xff, o3 = (ro >> 24) & 0xff;
        fo.x = o0 > 0 ? rsqrtf((float)o0) : 1.0f;
        fo.y = o1 > 0 ? rsqrtf((float)o1) : 1.0f;
        fo.z = o2 > 0 ? rsqrtf((float)o2) : 1.0f;
        fo.w = o3 > 0 ? rsqrtf((float)o3) : 1.0f;
        *(int4*)&deg_in[w * 4]     = dg;
        *(float4*)&norm_in[w * 4]  = fi;
        *(float4*)&norm_out[w * 4] = fo;
        mysum = d0 + d1 + d2 + d3;
    }
#pragma unroll
    for (int off = 32; off; off >>= 1) mysum += __shfl_xor(mysum, off, 64);
    if ((threadIdx.x & 63) == 0) red[threadIdx.x >> 6] = mysum;
    __syncthreads();
    if (threadIdx.x == 0) bsum[blockIdx.x] = red[0] + red[1] + red[2] + red[3];
}

// ---------------- wave-parallel scan of block sums ----------------
__global__ void k_bscan(const int* __restrict__ bsum, int* __restrict__ bofs,
                        int* __restrict__ row_ofs, int nb) {
    int lane = threadIdx.x;   // 64 lanes; nb <= 128
    int v0 = (lane * 2     < nb) ? bsum[lane * 2]     : 0;
    int v1 = (lane * 2 + 1 < nb) ? bsum[lane * 2 + 1] : 0;
    int pair = v0 + v1;
    int pre = pair;
#pragma unroll
    for (int off = 1; off < 64; off <<= 1) {
        int u = __shfl_up(pre, off, 64);
        if (lane >= off) pre += u;
    }
    int base = pre - pair;    // exclusive prefix of this pair
    if (lane * 2     < nb) bofs[lane * 2]     = base;
    if (lane * 2 + 1 < nb) bofs[lane * 2 + 1] = base + v0;
    if (lane == 63) { bofs[nb] = pre; row_ofs[NN] = pre; }  // pre == NE
}

__global__ void k_scan(const int* __restrict__ deg_in, const int* __restrict__ bofs,
                       int* __restrict__ row_ofs) {
    __shared__ int wofs[4];
    int t = threadIdx.x;
    int base = blockIdx.x * 1024 + t * 4;
    int d[4];
#pragma unroll
    for (int k = 0; k < 4; ++k) {
        int n = base + k;
        d[k] = (n < NN) ? deg_in[n] : 0;
    }
    int loc = d[0] + d[1] + d[2] + d[3];
    int v = loc;
    int lane = t & 63;
#pragma unroll
    for (int off = 1; off < 64; off <<= 1) {
        int u = __shfl_up(v, off, 64);
        if (lane >= off) v += u;
    }
    if (lane == 63) wofs[t >> 6] = v;
    __syncthreads();
    int w = t >> 6;
    int wbase = 0;
    if (w > 0) wbase += wofs[0];
    if (w > 1) wbase += wofs[1];
    if (w > 2) wbase += wofs[2];
    int excl = bofs[blockIdx.x] + wbase + (v - loc);
#pragma unroll
    for (int k = 0; k < 4; ++k) {
        int n = base + k;
        if (n < NN) { row_ofs[n] = excl; excl += d[k]; }
    }
}

// ---------------- atomic-free CSR fill ----------------
__global__ void k_replay(const int* __restrict__ src, const int* __restrict__ dst,
                         const uint* __restrict__ base_bytes, const unsigned char* __restrict__ lr,
                         const int* __restrict__ row_ofs, int* __restrict__ csr_src) {
    int e = blockIdx.x * blockDim.x + threadIdx.x;
    if (e < NE) {
        int d  = dst[e];
        int sl = e / EPS;
        uint pw = base_bytes[(size_t)sl * NW + (d >> 2)];
        int b = (int)((pw >> ((d & 3) * 8)) & 0xffu);
        csr_src[row_ofs[d] + b + (int)lr[e]] = src[e];
    }
}

// ---------------- MFMA projection: y = f16((x .* norm_out) @ W1) ----------------
__global__ void __launch_bounds__(256)
k_proj(const float* __restrict__ x, const float* __restrict__ norm_out,
       const float* __restrict__ W1, _Float16* __restrict__ y) {
    int lane = threadIdx.x & 63;
    int col  = lane & 15;
    int kh   = lane >> 4;
    f16x8 wf[4][2];
#pragma unroll
    for (int t = 0; t < 4; ++t)
#pragma unroll
        for (int s = 0; s < 2; ++s)
#pragma unroll
            for (int j = 0; j < 8; ++j)
                wf[t][s][j] = (_Float16)W1[(s * 32 + kh * 8 + j) * 64 + t * 16 + col];
    int tile = blockIdx.x * 4 + (threadIdx.x >> 6);
    if (tile >= NN / 16) return;
    int base = tile * 16;
    int row  = base + col;
    float no = norm_out[row];
    const float* xr = &x[(size_t)row * 64 + kh * 8];
    f16x8 af[2];
#pragma unroll
    for (int s = 0; s < 2; ++s) {
        float4 v0 = *(const float4*)&xr[s * 32];
        float4 v1 = *(const float4*)&xr[s * 32 + 4];
        af[s][0] = (_Float16)(v0.x * no); af[s][1] = (_Float16)(v0.y * no);
        af[s][2] = (_Float16)(v0.z * no); af[s][3] = (_Float16)(v0.w * no);
        af[s][4] = (_Float16)(v1.x * no); af[s][5] = (_Float16)(v1.y * no);
        af[s][6] = (_Float16)(v1.z * no); af[s][7] = (_Float16)(v1.w * no);
    }
    f32x4 acc[4];
#pragma unroll
    for (int t = 0; t < 4; ++t) acc[t] = (f32x4){0.f, 0.f, 0.f, 0.f};
#pragma unroll
    for (int t = 0; t < 4; ++t) {
        acc[t] = __builtin_amdgcn_mfma_f32_16x16x32_f16(af[0], wf[t][0], acc[t], 0, 0, 0);
        acc[t] = __builtin_amdgcn_mfma_f32_16x16x32_f16(af[1], wf[t][1], acc[t], 0, 0, 0);
    }
#pragma unroll
    for (int t = 0; t < 4; ++t)
#pragma unroll
        for (int r = 0; r < 4; ++r)
            y[(size_t)(base + kh * 4 + r) * 64 + t * 16 + col] = (_Float16)acc[t][r];
}

// ---------------- aggregate y (f16 gather) + relu/W2 epilogue ----------------
// persistent grid, 4 waves/block, wave = 1 node, 4 quarters x 4-deep unroll
// = 16 edges in flight per wave.
__device__ inline float2 up2(uint u) {
    f16x2 p = __builtin_bit_cast(f16x2, u);
    return make_float2((float)p.x, (float)p.y);
}

__global__ void __launch_bounds__(256)
k_agg1(const int* __restrict__ csr_src, const int* __restrict__ row_ofs,
       const uint* __restrict__ xb, const float* __restrict__ norm_in,
       const float* __restrict__ norm_out,
       const float* __restrict__ b1, const float* __restrict__ W2,
       float* __restrict__ z) {
    int tid = threadIdx.x;
    int lane = tid & 63, q = lane >> 4, lq = lane & 15;
    float4 bb = *(const float4*)&b1[lq * 4];
    float4 ww = *(const float4*)&W2[lq * 4];
    const size_t lqo = (size_t)(lq << 3);
    for (int n = blockIdx.x * 4 + (tid >> 6); n < NN; n += AGG_GRID * 4) {
        int beg = row_ofs[n], end = row_ofs[n + 1];
        float a0 = 0, a1 = 0, a2 = 0, a3 = 0;
        int ei = beg + q;
        for (; ei + 12 < end; ei += 16) {     // 16 edges in flight per wave
            int s0 = csr_src[ei], s1 = csr_src[ei + 4];
            int s2 = csr_src[ei + 8], s3 = csr_src[ei + 12];
            uint2 u0 = *(const uint2*)((const char*)xb + ((size_t)s0 << 7) + lqo);
            uint2 u1 = *(const uint2*)((const char*)xb + ((size_t)s1 << 7) + lqo);
            uint2 u2 = *(const uint2*)((const char*)xb + ((size_t)s2 << 7) + lqo);
            uint2 u3 = *(const uint2*)((const char*)xb + ((size_t)s3 << 7) + lqo);
            float2 p0 = up2(u0.x), r0 = up2(u0.y);
            float2 p1 = up2(u1.x), r1 = up2(u1.y);
            float2 p2 = up2(u2.x), r2 = up2(u2.y);
            float2 p3 = up2(u3.x), r3 = up2(u3.y);
            a0 += (p0.x + p1.x) + (p2.x + p3.x);
            a1 += (p0.y + p1.y) + (p2.y + p3.y);
            a2 += (r0.x + r1.x) + (r2.x + r3.x);
            a3 += (r0.y + r1.y) + (r2.y + r3.y);
        }
        for (; ei < end; ei += 4) {           // <=3 tail edges per quarter
            int s0 = csr_src[ei];
            uint2 u0 = *(const uint2*)((const char*)xb + ((size_t)s0 << 7) + lqo);
            float2 p0 = up2(u0.x), r0 = up2(u0.y);
            a0 += p0.x; a1 += p0.y; a2 += r0.x; a3 += r0.y;
        }
        a0 += __shfl_xor(a0, 16, 64); a0 += __shfl_xor(a0, 32, 64);
        a1 += __shfl_xor(a1, 16, 64); a1 += __shfl_xor(a1, 32, 64);
        a2 += __shfl_xor(a2, 16, 64); a2 += __shfl_xor(a2, 32, 64);
        a3 += __shfl_xor(a3, 16, 64); a3 += __shfl_xor(a3, 32, 64);
        float nin = norm_in[n];
        float h0 = fmaxf(a0 * nin + bb.x, 0.0f);
        float h1 = fmaxf(a1 * nin + bb.y, 0.0f);
        float h2 = fmaxf(a2 * nin + bb.z, 0.0f);
        float h3 = fmaxf(a3 * nin + bb.w, 0.0f);
        float zv = h0 * ww.x + h1 * ww.y + h2 * ww.z + h3 * ww.w;
#pragma unroll
        for (int off = 8; off; off >>= 1) zv += __shfl_xor(zv, off, 64);
        if (lane == 0) z[n] = zv * norm_out[n];
    }
}

// ---------------- layer 2 gather + sigmoid ----------------
__global__ void k_out2(const int* __restrict__ csr_src, const int* __restrict__ row_ofs,
                       const float* __restrict__ z, const float* __restrict__ norm_in,
                       const float* __restrict__ b2, float* __restrict__ out) {
    int n = blockIdx.x * blockDim.x + threadIdx.x;
    if (n < NN) {
        int beg = row_ofs[n], end = row_ofs[n + 1];
        float a = 0.0f;
        int i = beg;
        for (; i + 3 < end; i += 4) {
            float z0 = z[csr_src[i]], z1 = z[csr_src[i + 1]];
            float z2 = z[csr_src[i + 2]], z3 = z[csr_src[i + 3]];
            a += (z0 + z1) + (z2 + z3);
        }
        for (; i < end; ++i) a += z[csr_src[i]];
        float v = a * norm_in[n] + b2[0];
        out[n] = 1.0f / (1.0f + expf(-v));
    }
}

// ---------------- launch ----------------

extern "C" void kernel_launch(void* const* d_in, const int* in_sizes, int n_in,
                              void* d_out, int out_size, void* d_ws, size_t ws_size,
                              hipStream_t stream) {
    const float* x   = (const float*)d_in[0];
    const int*   src = (const int*)d_in[1];
    const int*   dst = (const int*)d_in[2];
    const float* W1  = (const float*)d_in[3];
    const float* b1  = (const float*)d_in[4];
    const float* W2  = (const float*)d_in[5];
    const float* b2  = (const float*)d_in[6];
    float* out = (float*)d_out;

    // ws layout (4B words). xb (3.2M words) aliases partial_in+lr+partial_out,
    // all dead after k_replay; k_proj runs after k_replay.
    uint* W0 = (uint*)d_ws;
    uint*          partial_in  = W0;                                  // 1.6M words
    unsigned char* lr          = (unsigned char*)(W0 + 1600000);      // 400K words
    uint*          partial_out = W0 + 2000000;                        // 1.6M words
    uint*          xb          = W0;                                  // 3.2M words (phase B)
    int*           csr_src     = (int*)(W0 + 3600000);                // 1.6M words
    int*           row_ofs     = (int*)(W0 + 5200000);                // NN+1
    int*           deg_in      = row_ofs + NN + 32;                   // NN
    float*         norm_in     = (float*)(deg_in + NN);               // NN
    float*         norm_out    = norm_in + NN;                        // NN
    float*         z           = norm_out + NN;                       // NN
    int*           bsum        = (int*)(z + NN);                      // 98
    int*           bofs        = bsum + 128;                          // 99

    int nb = (NN + 1023) / 1024;   // 98

    k_hist   <<<dim3(S, 2), 256, 0, stream>>>(src, dst, partial_in, partial_out, lr);
    k_degnorm<<<nb, 256, 0, stream>>>(partial_in, partial_out, deg_in, norm_in,
                                      norm_out, bsum);
    k_bscan  <<<1, 64, 0, stream>>>(bsum, bofs, row_ofs, nb);
    k_scan   <<<nb, 256, 0, stream>>>(deg_in, bofs, row_ofs);
    k_replay <<<(NE + 255) / 256, 256, 0, stream>>>(src, dst, partial_in, lr, row_ofs, csr_src);

    k_proj   <<<(NN / 16 + 3) / 4, 256, 0, stream>>>(x, norm_out, W1, (_Float16*)xb);
    k_agg1   <<<AGG_GRID, 256, 0, stream>>>(csr_src, row_ofs, xb, norm_in, norm_out,
                                            b1, W2, z);
    k_out2   <<<(NN + 255) / 256, 256, 0, stream>>>(csr_src, row_ofs, z, norm_in, b2, out);
}